// Round 3
// baseline (260.143 us; speedup 1.0000x reference)
//
#include <hip/hip_runtime.h>

// BinaryMatchAttention: out[b,d] = sum_s prod_k(1-|x[b,s,96+k]-qbit[k]|) * x[b,s,d], d<96
// x: (8, 32768, 128) fp32, query_addr: int scalar, out: (8, 96) fp32.
//
// Fused single kernel: each block streams its 128-row slice, writes a 96-float
// partial to d_ws, then takes a per-batch ticket; the last block of each batch
// reduces that batch's 256 partials and writes d_out. No stage-2 launch.

constexpr int B = 8;
constexpr int S = 32768;
constexpr int D4 = 32;            // float4 columns per row (128 floats)
constexpr int VAL4 = 24;          // value float4 columns (96 floats)
constexpr int ROWS_PER_STEP = 8;  // 256 threads / 32 columns
constexpr int BLOCKS_PER_B = 256;
constexpr int SPB = S / BLOCKS_PER_B;       // 128 rows per block
constexpr int ITERS = SPB / ROWS_PER_STEP;  // 16
constexpr size_t CNT_OFF = 4u << 20;        // counters live 4 MiB into d_ws

__global__ __launch_bounds__(256)
void bma_fused(const float* __restrict__ x, const int* __restrict__ qaddr,
               float* __restrict__ partial, unsigned* __restrict__ cnt,
               float* __restrict__ out) {
    const int t    = threadIdx.x;
    const int c    = t & 31;        // float4 column
    const int rg   = t >> 5;        // row group 0..7
    const int lane = t & 63;
    const int b    = blockIdx.x / BLOCKS_PER_B;
    const int s0   = (blockIdx.x % BLOCKS_PER_B) * SPB;

    const unsigned qa = (unsigned)qaddr[0];
    float qb0 = 0.f, qb1 = 0.f, qb2 = 0.f, qb3 = 0.f;
    if (c >= 24 && c < 28) {
        const int k0 = (c - 24) * 4;
        qb0 = (float)((qa >> (k0 + 0)) & 1u);
        qb1 = (float)((qa >> (k0 + 1)) & 1u);
        qb2 = (float)((qa >> (k0 + 2)) & 1u);
        qb3 = (float)((qa >> (k0 + 3)) & 1u);
    }

    const float4* __restrict__ xb =
        reinterpret_cast<const float4*>(x) + (long)b * S * D4;
    const int src = (lane & 32) | 24;  // broadcast source lane within this row

    float4 acc = make_float4(0.f, 0.f, 0.f, 0.f);

    #pragma unroll 4
    for (int i = 0; i < ITERS; ++i) {
        const int s = s0 + rg + i * ROWS_PER_STEP;
        float4 v = make_float4(0.f, 0.f, 0.f, 0.f);
        if (c < 28) v = xb[(long)s * D4 + c];   // skip dead cols 112..127

        float p = 1.0f;
        if (c >= 24 && c < 28) {
            p = (1.0f - fabsf(v.x - qb0)) * (1.0f - fabsf(v.y - qb1)) *
                (1.0f - fabsf(v.z - qb2)) * (1.0f - fabsf(v.w - qb3));
        }
        // product across the aligned 4-lane group {24..27} / {56..59}
        p *= __shfl_xor(p, 1);
        p *= __shfl_xor(p, 2);
        const float w = __shfl(p, src, 64);     // broadcast to the row's lanes

        if (c < VAL4) {
            acc.x = fmaf(w, v.x, acc.x);
            acc.y = fmaf(w, v.y, acc.y);
            acc.z = fmaf(w, v.z, acc.z);
            acc.w = fmaf(w, v.w, acc.w);
        }
    }

    // block-level reduce of the 8 row-groups → 96-float partial
    __shared__ float4 red[256];
    __shared__ bool slast;
    red[t] = acc;
    __syncthreads();
    if (t < 32) {
        float4 sum = red[t];
        #pragma unroll
        for (int g = 1; g < 8; ++g) {
            float4 o = red[t + 32 * g];
            sum.x += o.x; sum.y += o.y; sum.z += o.z; sum.w += o.w;
        }
        if (t < VAL4)
            reinterpret_cast<float4*>(partial)[(long)blockIdx.x * VAL4 + t] = sum;
    }

    // ticket: last block of this batch does the final reduction.
    // __syncthreads() drains vmcnt → partial stores are in L2 before the fence.
    __syncthreads();
    if (t == 0) {
        __threadfence();                         // release: write back to coherent point
        unsigned old = atomicAdd(&cnt[b], 1u);   // agent-scope
        slast = (old == (unsigned)(BLOCKS_PER_B - 1));
    }
    __syncthreads();
    if (!slast) return;
    __threadfence();                             // acquire: invalidate stale cache lines

    const float4* __restrict__ pp =
        reinterpret_cast<const float4*>(partial) + (long)b * BLOCKS_PER_B * VAL4;
    float4 racc = make_float4(0.f, 0.f, 0.f, 0.f);
    if (c < VAL4) {
        #pragma unroll 4
        for (int chunk = rg; chunk < BLOCKS_PER_B; chunk += ROWS_PER_STEP) {
            float4 v = pp[(long)chunk * VAL4 + c];
            racc.x += v.x; racc.y += v.y; racc.z += v.z; racc.w += v.w;
        }
    }
    __syncthreads();   // red[] reuse is safe: every thread passed its last read
    red[t] = racc;
    __syncthreads();
    if (t < VAL4) {
        float4 sum = red[t];
        #pragma unroll
        for (int g = 1; g < 8; ++g) {
            float4 o = red[t + 32 * g];
            sum.x += o.x; sum.y += o.y; sum.z += o.z; sum.w += o.w;
        }
        reinterpret_cast<float4*>(out)[(long)b * VAL4 + t] = sum;
    }
}

extern "C" void kernel_launch(void* const* d_in, const int* in_sizes, int n_in,
                              void* d_out, int out_size, void* d_ws, size_t ws_size,
                              hipStream_t stream) {
    const float* x   = (const float*)d_in[0];
    const int*   qa  = (const int*)d_in[1];
    float*       out = (float*)d_out;
    float*       ws  = (float*)d_ws;                           // partials: 768 KiB
    unsigned*    cnt = (unsigned*)((char*)d_ws + CNT_OFF);     // 8 ticket counters

    hipMemsetAsync(cnt, 0, B * sizeof(unsigned), stream);
    bma_fused<<<dim3(B * BLOCKS_PER_B), dim3(256), 0, stream>>>(x, qa, ws, cnt, out);
}

// Round 4
// 192.557 us; speedup vs baseline: 1.3510x; 1.3510x over previous
//
#include <hip/hip_runtime.h>

// BinaryMatchAttention: out[b,d] = sum_s prod_k(1-|x[b,s,96+k]-qbit[k]|) * x[b,s,d], d<96
// x: (8, 32768, 128) fp32, query_addr: int scalar, out: (8, 96) fp32.
//
// Stage 1 (per block = 128 rows): phase 1 computes all row weights into LDS
// (only place with cross-lane ops); phase 2 streams values with zero cross-lane
// ops, full coalescing, independent loads. Stage 2 reduces 256 partials/batch.

constexpr int B = 8;
constexpr int S = 32768;
constexpr int D4 = 32;            // float4 columns per row (128 floats)
constexpr int VAL4 = 24;          // value float4 columns (96 floats)
constexpr int BLOCKS_PER_B = 256;
constexpr int SPB = S / BLOCKS_PER_B;          // 128 rows per block
constexpr int ROWS_PER_ITER = 32;              // phase 2: 256 thr / 8 lanes-per-row
constexpr int P2_ITERS = SPB / ROWS_PER_ITER;  // 4

__global__ __launch_bounds__(256)
void bma_stage1(const float* __restrict__ x, const int* __restrict__ qaddr,
                float* __restrict__ partial) {
    const int t  = threadIdx.x;
    const int b  = blockIdx.x / BLOCKS_PER_B;
    const int s0 = (blockIdx.x % BLOCKS_PER_B) * SPB;

    const float4* __restrict__ xb =
        reinterpret_cast<const float4*>(x) + (long)b * S * D4;

    __shared__ float  wlds[SPB];            // per-row weights
    __shared__ float4 red[32][VAL4 + 1];    // +1 float4 pad vs bank aliasing

    // ---- phase 1: weights for all 128 rows (one pass, 2 key-float4s/thread)
    {
        const unsigned qa  = (unsigned)qaddr[0];
        const int row  = t >> 1;            // 0..127
        const int h    = t & 1;             // which 8-bit half of the key
        const long rb  = (long)(s0 + row) * D4;
        const float4 k0 = xb[rb + 24 + 2 * h];
        const float4 k1 = xb[rb + 25 + 2 * h];
        const int base = h * 8;
        float p = 1.0f;
        p *= 1.0f - fabsf(k0.x - (float)((qa >> (base + 0)) & 1u));
        p *= 1.0f - fabsf(k0.y - (float)((qa >> (base + 1)) & 1u));
        p *= 1.0f - fabsf(k0.z - (float)((qa >> (base + 2)) & 1u));
        p *= 1.0f - fabsf(k0.w - (float)((qa >> (base + 3)) & 1u));
        p *= 1.0f - fabsf(k1.x - (float)((qa >> (base + 4)) & 1u));
        p *= 1.0f - fabsf(k1.y - (float)((qa >> (base + 5)) & 1u));
        p *= 1.0f - fabsf(k1.z - (float)((qa >> (base + 6)) & 1u));
        p *= 1.0f - fabsf(k1.w - (float)((qa >> (base + 7)) & 1u));
        p *= __shfl_xor(p, 1);              // combine the two halves (same wave)
        if (h == 0) wlds[row] = p;
    }
    __syncthreads();

    // ---- phase 2: pure streaming, no cross-lane ops.
    // thread (rg = t>>3, f = t&7) reads rows rg, rg+32, rg+64, rg+96;
    // per row: 3 float4 loads at cols f, f+8, f+16 (8 lanes = one 128B line).
    const int f  = t & 7;
    const int rg = t >> 3;                  // 0..31
    float4 a0 = make_float4(0.f, 0.f, 0.f, 0.f);
    float4 a1 = a0, a2 = a0;

    #pragma unroll
    for (int i = 0; i < P2_ITERS; ++i) {
        const int  row  = i * ROWS_PER_ITER + rg;
        const long base = (long)(s0 + row) * D4;
        const float4 v0 = xb[base + f];
        const float4 v1 = xb[base + f + 8];
        const float4 v2 = xb[base + f + 16];
        const float  w  = wlds[row];        // 8-lane broadcast, conflict-free
        a0.x = fmaf(w, v0.x, a0.x); a0.y = fmaf(w, v0.y, a0.y);
        a0.z = fmaf(w, v0.z, a0.z); a0.w = fmaf(w, v0.w, a0.w);
        a1.x = fmaf(w, v1.x, a1.x); a1.y = fmaf(w, v1.y, a1.y);
        a1.z = fmaf(w, v1.z, a1.z); a1.w = fmaf(w, v1.w, a1.w);
        a2.x = fmaf(w, v2.x, a2.x); a2.y = fmaf(w, v2.y, a2.y);
        a2.z = fmaf(w, v2.z, a2.z); a2.w = fmaf(w, v2.w, a2.w);
    }

    red[rg][f]      = a0;
    red[rg][f + 8]  = a1;
    red[rg][f + 16] = a2;
    __syncthreads();

    if (t < VAL4) {
        float4 sum = make_float4(0.f, 0.f, 0.f, 0.f);
        #pragma unroll 8
        for (int g = 0; g < 32; ++g) {
            const float4 o = red[g][t];
            sum.x += o.x; sum.y += o.y; sum.z += o.z; sum.w += o.w;
        }
        reinterpret_cast<float4*>(partial)[(long)blockIdx.x * VAL4 + t] = sum;
    }
}

// partial: [B*BLOCKS_PER_B][96] floats -> out: [B][96].
__global__ __launch_bounds__(256)
void bma_stage2(const float* __restrict__ partial, float* __restrict__ out) {
    const int t  = threadIdx.x;
    const int c  = t & 31;   // float4 column (0..23 active)
    const int rg = t >> 5;   // chunk group 0..7
    const int b  = blockIdx.x;

    const float4* __restrict__ pp =
        reinterpret_cast<const float4*>(partial) + (long)b * BLOCKS_PER_B * VAL4;

    float4 acc = make_float4(0.f, 0.f, 0.f, 0.f);
    if (c < VAL4) {
        #pragma unroll 4
        for (int chunk = rg; chunk < BLOCKS_PER_B; chunk += 8) {
            const float4 v = pp[(long)chunk * VAL4 + c];
            acc.x += v.x; acc.y += v.y; acc.z += v.z; acc.w += v.w;
        }
    }

    __shared__ float4 red[256];
    red[t] = acc;
    __syncthreads();
    if (t < VAL4) {
        float4 sum = red[t];
        #pragma unroll
        for (int g = 1; g < 8; ++g) {
            const float4 o = red[t + 32 * g];
            sum.x += o.x; sum.y += o.y; sum.z += o.z; sum.w += o.w;
        }
        reinterpret_cast<float4*>(out)[(long)b * VAL4 + t] = sum;
    }
}

extern "C" void kernel_launch(void* const* d_in, const int* in_sizes, int n_in,
                              void* d_out, int out_size, void* d_ws, size_t ws_size,
                              hipStream_t stream) {
    const float* x   = (const float*)d_in[0];
    const int*   qa  = (const int*)d_in[1];
    float*       out = (float*)d_out;
    float*       ws  = (float*)d_ws;   // partials: B*256*96*4 = 768 KiB

    bma_stage1<<<dim3(B * BLOCKS_PER_B), dim3(256), 0, stream>>>(x, qa, ws);
    bma_stage2<<<dim3(B), dim3(256), 0, stream>>>(ws, out);
}